// Round 2
// baseline (74.779 us; speedup 1.0000x reference)
//
#include <hip/hip_runtime.h>

// 4x4 spiking array multiplier == exact 4-bit x 4-bit binary multiply.
// Inputs A, B: (N,4) float32 in {0,1}. Output: (N,8) float32 = bits of a*b.
//
// Memory-bound: 256 MiB total @ ~6.3 TB/s achievable -> ~43 us floor.
// This version: 2 rows per thread so every wave memory instruction is
// fully dense (loads 32 B/lane contiguous, stores 64 B/lane contiguous),
// plus nontemporal hints (zero reuse -> don't pollute L2/L3).

typedef float f4 __attribute__((ext_vector_type(4)));

__device__ __forceinline__ int pack4(f4 v) {
    return (v.x != 0.0f ? 1 : 0)
         | (v.y != 0.0f ? 2 : 0)
         | (v.z != 0.0f ? 4 : 0)
         | (v.w != 0.0f ? 8 : 0);
}

__device__ __forceinline__ void unpack8(int p, f4& lo, f4& hi) {
    lo.x = (float)( p       & 1);
    lo.y = (float)((p >> 1) & 1);
    lo.z = (float)((p >> 2) & 1);
    lo.w = (float)((p >> 3) & 1);
    hi.x = (float)((p >> 4) & 1);
    hi.y = (float)((p >> 5) & 1);
    hi.z = (float)((p >> 6) & 1);
    hi.w = (float)((p >> 7) & 1);
}

__global__ __launch_bounds__(256) void mult4x4_kernel(
    const f4* __restrict__ A4,   // N rows, 1 float4 each
    const f4* __restrict__ B4,
    f4* __restrict__ O4,         // N rows, 2 float4 each
    int npair)                   // N/2: row pairs
{
    int t = blockIdx.x * blockDim.x + threadIdx.x;
    if (t >= npair) return;

    f4 a0 = __builtin_nontemporal_load(A4 + 2 * t);
    f4 a1 = __builtin_nontemporal_load(A4 + 2 * t + 1);
    f4 b0 = __builtin_nontemporal_load(B4 + 2 * t);
    f4 b1 = __builtin_nontemporal_load(B4 + 2 * t + 1);

    int p0 = pack4(a0) * pack4(b0);
    int p1 = pack4(a1) * pack4(b1);

    f4 o0, o1, o2, o3;
    unpack8(p0, o0, o1);
    unpack8(p1, o2, o3);

    __builtin_nontemporal_store(o0, O4 + 4 * t);
    __builtin_nontemporal_store(o1, O4 + 4 * t + 1);
    __builtin_nontemporal_store(o2, O4 + 4 * t + 2);
    __builtin_nontemporal_store(o3, O4 + 4 * t + 3);
}

extern "C" void kernel_launch(void* const* d_in, const int* in_sizes, int n_in,
                              void* d_out, int out_size, void* d_ws, size_t ws_size,
                              hipStream_t stream)
{
    const f4* A4 = (const f4*)d_in[0];
    const f4* B4 = (const f4*)d_in[1];
    f4* O4 = (f4*)d_out;

    int n = in_sizes[0] / 4;        // number of rows (4M)
    int npair = n / 2;              // N is a multiple of 2
    int block = 256;
    int grid = (npair + block - 1) / block;
    mult4x4_kernel<<<grid, block, 0, stream>>>(A4, B4, O4, npair);
}

// Round 3
// 41.801 us; speedup vs baseline: 1.7889x; 1.7889x over previous
//
#include <hip/hip_runtime.h>

// 4x4 spiking array multiplier == exact 4-bit x 4-bit binary multiply.
// Inputs A, B: (N,4) float32 in {0,1}. Output: (N,8) float32 = bits of a*b.
//
// Memory-bound: 256 MiB total @ ~6.3 TB/s -> ~43 us floor.
// Layout lesson (round 2): per-INSTRUCTION lane density is what matters.
// Here: one output float4 per thread -> every store instruction is fully
// dense (lane i writes base + 16*i, 1 KiB/wave). Loads are duplicated
// across lane pairs (same 16 B row) -- no extra HBM traffic.

typedef float f4 __attribute__((ext_vector_type(4)));

__global__ __launch_bounds__(256) void mult4x4_kernel(
    const f4* __restrict__ A4,   // N rows, 1 float4 each
    const f4* __restrict__ B4,
    f4* __restrict__ O4,         // 2N float4s
    int nout)                    // 2N
{
    int t = blockIdx.x * blockDim.x + threadIdx.x;
    if (t >= nout) return;

    int r = t >> 1;              // row index (lane pairs share a row)
    f4 a = A4[r];
    f4 b = B4[r];

    int ai = (a.x != 0.0f ? 1 : 0)
           | (a.y != 0.0f ? 2 : 0)
           | (a.z != 0.0f ? 4 : 0)
           | (a.w != 0.0f ? 8 : 0);
    int bi = (b.x != 0.0f ? 1 : 0)
           | (b.y != 0.0f ? 2 : 0)
           | (b.z != 0.0f ? 4 : 0)
           | (b.w != 0.0f ? 8 : 0);

    int p = (ai * bi) >> ((t & 1) * 4);   // this thread's nibble of the product

    f4 o;
    o.x = (float)( p       & 1);
    o.y = (float)((p >> 1) & 1);
    o.z = (float)((p >> 2) & 1);
    o.w = (float)((p >> 3) & 1);

    O4[t] = o;                   // fully dense per wave store
}

extern "C" void kernel_launch(void* const* d_in, const int* in_sizes, int n_in,
                              void* d_out, int out_size, void* d_ws, size_t ws_size,
                              hipStream_t stream)
{
    const f4* A4 = (const f4*)d_in[0];
    const f4* B4 = (const f4*)d_in[1];
    f4* O4 = (f4*)d_out;

    int n = in_sizes[0] / 4;     // rows
    int nout = 2 * n;            // output float4s
    int block = 256;
    int grid = (nout + block - 1) / block;
    mult4x4_kernel<<<grid, block, 0, stream>>>(A4, B4, O4, nout);
}